// Round 21
// baseline (191.186 us; speedup 1.0000x reference)
//
#include <hip/hip_runtime.h>
#include <math.h>

#define F1 100
#define F2 200
#define KM 12          // Chebyshev moments (rho~17 => trunc far below fp32 roundoff)
#define BW_LOG 9
#define BW 512

__device__ __forceinline__ float siluf(float v) {
    return v / (1.0f + expf(-v));   // precise
}
__device__ __forceinline__ float silu_fast(float v) {
    return __fdividef(v, 1.0f + __expf(-v));
}

// Fused prologue: batch bounds (block 0) + zero pooled (all blocks) + zero bcnt/amax/gbar (block 1).
#define PREP_BLOCKS 16
__global__ __launch_bounds__(256) void k_prep(
    const int* __restrict__ batch, int N, int G, int nbk,
    int* __restrict__ starts, int* __restrict__ counts,
    double* __restrict__ pooled, int* __restrict__ bcnt, unsigned* __restrict__ amax,
    int* __restrict__ gbar) {
    int t = threadIdx.x;
    int b = blockIdx.x;
    for (int idx = b * 256 + t; idx < G * F2; idx += PREP_BLOCKS * 256)
        pooled[idx] = 0.0;
    if (b == 1) {
        for (int i = t; i < nbk; i += 256) bcnt[i] = 0;
        if (t == 0) *amax = 0u;
        if (t < 8) gbar[t] = 0;
    }
    if (b == 0) {
        if (t <= G) {
            int lo = 0, hi = N;
            while (lo < hi) {
                int mid = (lo + hi) >> 1;
                if (batch[mid] < t) lo = mid + 1; else hi = mid;
            }
            starts[t] = lo;
        }
        __syncthreads();
        if (t < G) counts[t] = starts[t + 1] - starts[t];
    }
}

// Device-scope grid barrier for the persistent build kernel.
// All GB_BLOCKS blocks are guaranteed co-resident (capacity: 3 blocks/CU by LDS,
// 240 blocks << 256 CUs * 3). Counters zeroed by k_prep each call.
__device__ __forceinline__ void gsync(int* ctr, int nblk) {
    __syncthreads();
    if (threadIdx.x == 0) {
        __threadfence();                       // release: drain prior global writes
        atomicAdd(ctr, 1);
        while (atomicAdd(ctr, 0) < nblk) { }   // device-scope spin
        __threadfence();                       // acquire: invalidate CU L1
    }
    __syncthreads();
}

// Persistent bucket-build: count -> scan -> scatter -> degoff -> fill in ONE kernel.
// Grid MUST be GB_BLOCKS x 512. Phase logic identical to the former 5 kernels.
#define GB_BLOCKS 240
#define CROUND 4096
#define CEPT 8          // CROUND / 512
__global__ __launch_bounds__(512) void k_bucket_build(
    const int* __restrict__ src, const int* __restrict__ dst,
    const float* __restrict__ x, int N, int E, int nbk,
    int* __restrict__ bcnt, int* __restrict__ bbase, int* __restrict__ bcur,
    unsigned long long* __restrict__ pairs,
    float* __restrict__ dinv, float* __restrict__ y, int* __restrict__ off,
    int* __restrict__ nbr, float2* __restrict__ aggxd, unsigned* __restrict__ amax,
    int* __restrict__ gbar) {
    // shared scratch union: scatter layout dominates (32KB stage + 5x2KB int arrays)
    __shared__ __align__(16) char raw[43008];
    int tid = threadIdx.x;
    int bid = blockIdx.x;

    // ---- Phase A: bucket histogram ----
    {
        int* hist = (int*)raw;
        for (int i = tid; i < nbk; i += 512) hist[i] = 0;
        __syncthreads();
        for (int e = bid * 512 + tid; e < E; e += GB_BLOCKS * 512)
            atomicAdd(&hist[dst[e] >> BW_LOG], 1);
        __syncthreads();
        for (int i = tid; i < nbk; i += 512)
            if (hist[i]) atomicAdd(&bcnt[i], hist[i]);
    }
    gsync(&gbar[0], GB_BLOCKS);

    // ---- Phase B: exclusive scan of bucket counts (block 0) ----
    if (bid == 0) {
        int* sh = (int*)raw;
        int v = (tid < nbk) ? bcnt[tid] : 0;
        sh[tid] = v;
        __syncthreads();
        for (int ofs = 1; ofs < 512; ofs <<= 1) {
            int u = (tid >= ofs) ? sh[tid - ofs] : 0;
            __syncthreads();
            sh[tid] += u;
            __syncthreads();
        }
        if (tid < nbk) { int ex = sh[tid] - v; bbase[tid] = ex; bcur[tid] = ex; }
        if (tid == 0) bbase[nbk] = E;
    }
    gsync(&gbar[1], GB_BLOCKS);

    // ---- Phase C: bucket-sorted scatter of (src,dst) pairs ----
    {
        unsigned long long* stage = (unsigned long long*)raw;          // 32768 B
        int* cnt    = (int*)(raw + 32768);
        int* scanb  = (int*)(raw + 34816);
        int* startx = (int*)(raw + 36864);
        int* cur    = (int*)(raw + 38912);
        int* gbase  = (int*)(raw + 40960);
        for (long long r0 = (long long)bid * CROUND; r0 < E; r0 += (long long)GB_BLOCKS * CROUND) {
            cnt[tid] = 0;
            __syncthreads();
            int ss[CEPT], dd[CEPT], bb[CEPT];
            bool va[CEPT];
            #pragma unroll
            for (int j = 0; j < CEPT; ++j) {
                long long e = r0 + j * 512 + tid;
                va[j] = (e < E);
                if (va[j]) {
                    ss[j] = src[e]; dd[j] = dst[e]; bb[j] = dd[j] >> BW_LOG;
                    atomicAdd(&cnt[bb[j]], 1);
                }
            }
            __syncthreads();
            scanb[tid] = cnt[tid];
            __syncthreads();
            for (int ofs = 1; ofs < 512; ofs <<= 1) {
                int u = (tid >= ofs) ? scanb[tid - ofs] : 0;
                __syncthreads();
                scanb[tid] += u;
                __syncthreads();
            }
            int ex = scanb[tid] - cnt[tid];
            startx[tid] = ex;
            cur[tid] = ex;
            if (tid < nbk && cnt[tid] > 0) gbase[tid] = atomicAdd(&bcur[tid], cnt[tid]);
            __syncthreads();
            int total = scanb[511];
            #pragma unroll
            for (int j = 0; j < CEPT; ++j) {
                if (va[j]) {
                    int slot = atomicAdd(&cur[bb[j]], 1);
                    stage[slot] = ((unsigned long long)(unsigned)dd[j] << 32) | (unsigned)ss[j];
                }
            }
            __syncthreads();
            for (int i = tid; i < total; i += 512) {
                unsigned long long p = stage[i];
                int b = (int)(p >> 32) >> BW_LOG;
                pairs[gbase[b] + (i - startx[b])] = p;
            }
            __syncthreads();
        }
    }
    gsync(&gbar[2], GB_BLOCKS);

    // ---- Phase D: per-bucket degree histogram + dinv + y + CSR off ----
    {
        int* dl = (int*)raw;
        int* sc = (int*)(raw + 2048);
        for (int b = bid; b < nbk; b += GB_BLOCKS) {
            dl[tid] = 0;
            __syncthreads();
            int beg = bbase[b], end = bbase[b + 1];
            for (int i = beg + tid; i < end; i += 512)
                atomicAdd(&dl[(int)(pairs[i] >> 32) & (BW - 1)], 1);
            __syncthreads();
            int node = (b << BW_LOG) + tid;
            int dg = dl[tid];
            if (node < N) {
                float d = 1.0f / sqrtf((float)dg + 1.0f);
                dinv[node] = d;
                y[node] = x[node] * d;
            }
            sc[tid] = dg;
            __syncthreads();
            for (int ofs = 1; ofs < BW; ofs <<= 1) {
                int u = (tid >= ofs) ? sc[tid - ofs] : 0;
                __syncthreads();
                sc[tid] += u;
                __syncthreads();
            }
            if (node < N) off[node] = beg + sc[tid] - dg;
            if (node == N - 1) off[N] = beg + sc[tid];
            __syncthreads();
        }
    }
    gsync(&gbar[3], GB_BLOCKS);

    // ---- Phase E: CSR fill + layer-1 scalar agg -> aggxd; block-max -> amax ----
    {
        int* offl  = (int*)raw;
        int* cur   = (int*)(raw + 2048);
        float* agg = (float*)(raw + 4096);
        for (int b = bid; b < nbk; b += GB_BLOCKS) {
            int node0 = b << BW_LOG;
            int node = node0 + tid;
            offl[tid] = (node < N) ? off[node] : 0;
            cur[tid] = 0;
            agg[tid] = 0.0f;
            __syncthreads();
            int beg = bbase[b], end = bbase[b + 1];
            for (int i = beg + tid; i < end; i += 512) {
                unsigned long long p = pairs[i];
                int s = (int)(p & 0xffffffffu);
                int d = (int)(p >> 32);
                int l = d & (BW - 1);
                int pos = atomicAdd(&cur[l], 1);
                nbr[offl[l] + pos] = s;
                atomicAdd(&agg[l], y[s]);
            }
            __syncthreads();
            float av = 0.0f;
            if (node < N) {
                float dn = dinv[node];
                float a = dn * (agg[tid] + y[node]);
                aggxd[node] = make_float2(a, dn);
                av = fabsf(a);
            }
            __syncthreads();
            agg[tid] = av;
            __syncthreads();
            for (int ofs = 256; ofs > 0; ofs >>= 1) {
                if (tid < ofs) agg[tid] = fmaxf(agg[tid], agg[tid + ofs]);
                __syncthreads();
            }
            if (tid == 0) atomicMax(amax, __float_as_uint(agg[0]));
            __syncthreads();
        }
    }
}

// Fit stage 1: Chebyshev coefficients cl[k][j] of g(a,j)=silu(a*W1[j]+b1[j]) on [-A,A].
__global__ __launch_bounds__(64) void k_fit_coef(
    const float* __restrict__ W1, const float* __restrict__ b1,
    const unsigned* __restrict__ amax_bits,
    double* __restrict__ cl /* [KM][F1] */, float* __restrict__ scal /* {A, invA} */) {
    int j = blockIdx.x;
    int i = threadIdx.x;
    float A = __uint_as_float(*amax_bits);
    if (!(A > 0.0f)) A = 1.0f;
    A *= 1.000001f;
    if (j == 0 && i == 0) { scal[0] = A; scal[1] = 1.0f / A; }
    const double PI = 3.14159265358979323846;
    double th = (i + 0.5) * (PI / 64.0);
    double xx = cos(th);
    double w = (double)W1[j] * (double)A;
    double u = w * xx + (double)b1[j];
    double f = u / (1.0 + exp(-u));
    double acc[KM];
    {
        double c0 = 1.0, c1 = xx;
        acc[0] = f;
        acc[1] = f * xx;
        #pragma unroll
        for (int k = 2; k < KM; ++k) {
            double c2 = 2.0 * xx * c1 - c0;
            acc[k] = f * c2;
            c0 = c1; c1 = c2;
        }
    }
    #pragma unroll
    for (int k = 0; k < KM; ++k) {
        double v = acc[k];
        for (int ofs = 32; ofs > 0; ofs >>= 1)
            v += __shfl_down(v, ofs);
        if (i == 0) cl[k * F1 + j] = v * ((k == 0 ? 1.0 : 2.0) / 64.0);
    }
}

// Fit stage 2: fold through W2: D[k][m] = sum_j cl[k][j] * W2[j][m].
__global__ __launch_bounds__(256) void k_fit_fold(
    const double* __restrict__ cl, const float* __restrict__ W2,
    float* __restrict__ Dmat /* [KM][F2] */) {
    __shared__ double scl[KM * F1];
    int tid = threadIdx.x;
    for (int idx = tid; idx < KM * F1; idx += 256) scl[idx] = cl[idx];
    __syncthreads();
    int idx = blockIdx.x * 256 + tid;
    if (idx >= KM * F2) return;
    int k = idx / F2, m = idx % F2;
    double s = 0.0;
    #pragma unroll 4
    for (int j = 0; j < F1; ++j)
        s += scl[k * F1 + j] * (double)W2[j * F2 + m];
    Dmat[idx] = (float)s;
}

// Fused moments + h2 + graph mean-pool: one block per 32 nodes.
#define P7_NODES 32
__global__ __launch_bounds__(256) void k_h2_pool7(
    const int* __restrict__ off, const int* __restrict__ nbr,
    const float2* __restrict__ aggxd, const float* __restrict__ scal,
    const float* __restrict__ Dmat, const float* __restrict__ b2,
    const int* __restrict__ batch, int N, double* __restrict__ pooled) {
    __shared__ float sM[P7_NODES][KM];   // 1.5 KB
    __shared__ int sbatch[P7_NODES];
    int tid = threadIdx.x;
    int base = blockIdx.x * P7_NODES;
    if (tid < P7_NODES) {
        int n = base + tid;
        sbatch[tid] = (n < N) ? batch[n] : -1;
    }
    int m = tid;
    bool act = (m < F2);
    float4 d4[KM / 4];
    float bb = 0.0f;
    if (act) {
        #pragma unroll
        for (int k = 0; k < KM / 4; ++k) {
            d4[k].x = Dmat[(4 * k + 0) * F2 + m];
            d4[k].y = Dmat[(4 * k + 1) * F2 + m];
            d4[k].z = Dmat[(4 * k + 2) * F2 + m];
            d4[k].w = Dmat[(4 * k + 3) * F2 + m];
        }
        bb = b2[m];
    }
    // ---- phase 1: moments for this block's 32 nodes (8 threads/node) ----
    {
        int g = tid >> 3;
        int l = tid & 7;
        int node = base + g;
        float invA = scal[1];
        float u[KM];
        #pragma unroll
        for (int k = 0; k < KM; ++k) u[k] = 0.0f;
        if (node < N) {
            int beg = off[node], end = off[node + 1];
            for (int e = beg + l; e < end; e += 8) {
                int s = nbr[e];
                float2 q = aggxd[s];
                float w = q.y;
                float xa = q.x * invA;
                float tx = xa + xa;
                float c0 = 1.0f, c1 = xa;
                u[0] += w;
                u[1] = fmaf(w, c1, u[1]);
                #pragma unroll
                for (int k = 2; k < KM; ++k) {
                    float c2 = fmaf(tx, c1, -c0);
                    u[k] = fmaf(w, c2, u[k]);
                    c0 = c1; c1 = c2;
                }
            }
        }
        #pragma unroll
        for (int k = 0; k < KM; ++k) {
            u[k] += __shfl_down(u[k], 4, 8);
            u[k] += __shfl_down(u[k], 2, 8);
            u[k] += __shfl_down(u[k], 1, 8);
        }
        if (l == 0 && node < N) {
            float2 sd = aggxd[node];
            float d0 = sd.y;
            float d00 = d0 * d0;
            float xa = sd.x * invA;
            float tx = xa + xa;
            float c0 = 1.0f, c1 = xa;
            sM[g][0] = fmaf(d0, u[0], d00);
            sM[g][1] = fmaf(d0, u[1], d00 * xa);
            #pragma unroll
            for (int k = 2; k < KM; ++k) {
                float c2 = fmaf(tx, c1, -c0);
                sM[g][k] = fmaf(d0, u[k], d00 * c2);
                c0 = c1; c1 = c2;
            }
        }
    }
    __syncthreads();
    // ---- phase 2: h2 + pooling (2-node ILP unroll) ----
    double pl = 0.0;
    int gcur = -1;
    int nlim = min(P7_NODES, N - base);
    int i = 0;
    for (; i + 1 < nlim; i += 2) {
        float p0 = bb, p1 = 0.f, p2 = 0.f, p3 = 0.f;
        float q0 = bb, q1 = 0.f, q2 = 0.f, q3 = 0.f;
        const float4* mA = (const float4*)&sM[i][0];
        const float4* mB = (const float4*)&sM[i + 1][0];
        #pragma unroll
        for (int k = 0; k < KM / 4; ++k) {
            float4 a = mA[k];
            float4 c = mB[k];
            p0 = fmaf(a.x, d4[k].x, p0); q0 = fmaf(c.x, d4[k].x, q0);
            p1 = fmaf(a.y, d4[k].y, p1); q1 = fmaf(c.y, d4[k].y, q1);
            p2 = fmaf(a.z, d4[k].z, p2); q2 = fmaf(c.z, d4[k].z, q2);
            p3 = fmaf(a.w, d4[k].w, p3); q3 = fmaf(c.w, d4[k].w, q3);
        }
        float preA = (p0 + p1) + (p2 + p3);
        float preB = (q0 + q1) + (q2 + q3);
        float hA = silu_fast(preA);
        float hB = silu_fast(preB);
        int g = sbatch[i];
        if (g != gcur) {
            if (gcur >= 0 && act) atomicAdd(&pooled[(size_t)gcur * F2 + m], pl);
            pl = 0.0;
            gcur = g;
        }
        if (act) pl += (double)hA;
        g = sbatch[i + 1];
        if (g != gcur) {
            if (gcur >= 0 && act) atomicAdd(&pooled[(size_t)gcur * F2 + m], pl);
            pl = 0.0;
            gcur = g;
        }
        if (act) pl += (double)hB;
    }
    if (i < nlim) {
        float p0 = bb, p1 = 0.f, p2 = 0.f, p3 = 0.f;
        const float4* mA = (const float4*)&sM[i][0];
        #pragma unroll
        for (int k = 0; k < KM / 4; ++k) {
            float4 a = mA[k];
            p0 = fmaf(a.x, d4[k].x, p0);
            p1 = fmaf(a.y, d4[k].y, p1);
            p2 = fmaf(a.z, d4[k].z, p2);
            p3 = fmaf(a.w, d4[k].w, p3);
        }
        float pre = (p0 + p1) + (p2 + p3);
        int g = sbatch[i];
        if (g != gcur) {
            if (gcur >= 0 && act) atomicAdd(&pooled[(size_t)gcur * F2 + m], pl);
            pl = 0.0;
            gcur = g;
        }
        if (act) pl += (double)silu_fast(pre);
    }
    if (gcur >= 0 && act) atomicAdd(&pooled[(size_t)gcur * F2 + m], pl);
}

// ---- fallback path kernels (ws too small for pairs) ----
#define SCHUNK 2048
__global__ __launch_bounds__(256) void k_scan_partial(const int* __restrict__ deg, int N,
                                                      int* __restrict__ partials) {
    __shared__ int red[256];
    int base = blockIdx.x * SCHUNK;
    int s = 0;
    for (int i = threadIdx.x; i < SCHUNK; i += 256) {
        int idx = base + i;
        if (idx < N) s += deg[idx];
    }
    red[threadIdx.x] = s;
    __syncthreads();
    for (int ofs = 128; ofs > 0; ofs >>= 1) {
        if (threadIdx.x < ofs) red[threadIdx.x] += red[threadIdx.x + ofs];
        __syncthreads();
    }
    if (threadIdx.x == 0) partials[blockIdx.x] = red[0];
}
__global__ __launch_bounds__(1024) void k_scan_blocks(int* __restrict__ partials, int nb) {
    __shared__ int sh[1024];
    int t = threadIdx.x;
    int v = (t < nb) ? partials[t] : 0;
    sh[t] = v;
    __syncthreads();
    for (int ofs = 1; ofs < 1024; ofs <<= 1) {
        int u = (t >= ofs) ? sh[t - ofs] : 0;
        __syncthreads();
        sh[t] += u;
        __syncthreads();
    }
    if (t < nb) partials[t] = sh[t] - v;
}
__global__ __launch_bounds__(256) void k_scan_final(const int* __restrict__ deg, int N,
                                                    const int* __restrict__ partials,
                                                    int* __restrict__ off) {
    __shared__ int sh[256];
    int base = blockIdx.x * SCHUNK;
    int i0 = base + threadIdx.x * 8;
    int v[8];
    int s = 0;
    #pragma unroll
    for (int j = 0; j < 8; ++j) {
        int idx = i0 + j;
        v[j] = (idx < N) ? deg[idx] : 0;
        s += v[j];
    }
    int mine = s;
    sh[threadIdx.x] = s;
    __syncthreads();
    for (int ofs = 1; ofs < 256; ofs <<= 1) {
        int u = (threadIdx.x >= ofs) ? sh[threadIdx.x - ofs] : 0;
        __syncthreads();
        sh[threadIdx.x] += u;
        __syncthreads();
    }
    int run = partials[blockIdx.x] + sh[threadIdx.x] - mine;
    #pragma unroll
    for (int j = 0; j < 8; ++j) {
        int idx = i0 + j;
        if (idx < N) { off[idx] = run; run += v[j]; }
    }
    if (N >= i0 && N <= i0 + 8) off[N] = run;
}
__global__ void k_count_deg(const int* __restrict__ dst, int E, int* __restrict__ deg) {
    int i = blockIdx.x * blockDim.x + threadIdx.x;
    if (i < E) atomicAdd(&deg[dst[i]], 1);
}
__global__ void k_dinv_self(const int* __restrict__ deg, const float* __restrict__ x, int N,
                            float* __restrict__ dinv, float* __restrict__ aggx) {
    int i = blockIdx.x * blockDim.x + threadIdx.x;
    if (i < N) {
        float d = 1.0f / sqrtf((float)deg[i] + 1.0f);
        dinv[i] = d;
        aggx[i] = x[i] * d * d;
    }
}
__global__ void k_fill_agg(const int* __restrict__ src, const int* __restrict__ dst, int E,
                           const int* __restrict__ off, int* __restrict__ cursor,
                           int* __restrict__ nbr,
                           const float* __restrict__ x, const float* __restrict__ dinv,
                           float* __restrict__ aggx) {
    int e = blockIdx.x * blockDim.x + threadIdx.x;
    if (e < E) {
        int s = src[e], d = dst[e];
        int p = atomicAdd(&cursor[d], 1);
        nbr[off[d] + p] = s;
        atomicAdd(&aggx[d], x[s] * dinv[s] * dinv[d]);
    }
}
__global__ __launch_bounds__(256) void k_aggh(
    const int* __restrict__ off, const int* __restrict__ nbr,
    const float* __restrict__ aggx, const float* __restrict__ dinv,
    const float* __restrict__ W1, const float* __restrict__ b1,
    int N, float* __restrict__ aggh) {
    int wave = threadIdx.x >> 6;
    int lane = threadIdx.x & 63;
    int n = blockIdx.x * 4 + wave;
    if (n >= N) return;
    int ja = lane, jb = lane + 64;
    float w1a = (ja < F1) ? W1[ja] : 0.0f;
    float b1a = (ja < F1) ? b1[ja] : 0.0f;
    float w1b = (jb < F1) ? W1[jb] : 0.0f;
    float b1b = (jb < F1) ? b1[jb] : 0.0f;
    float d0 = dinv[n];
    float a0 = aggx[n];
    float accA = silu_fast(fmaf(a0, w1a, b1a)) * (d0 * d0);
    float accB = silu_fast(fmaf(a0, w1b, b1b)) * (d0 * d0);
    int beg = off[n], end = off[n + 1];
    for (int t = beg; t < end; t += 64) {
        int cnt = min(64, end - t);
        float sa = 0.0f, sw = 0.0f;
        if (lane < cnt) {
            int s = nbr[t + lane];
            sa = aggx[s];
            sw = dinv[s] * d0;
        }
        for (int i = 0; i < cnt; ++i) {
            float ai = __shfl(sa, i);
            float wi = __shfl(sw, i);
            accA = fmaf(wi, silu_fast(fmaf(ai, w1a, b1a)), accA);
            accB = fmaf(wi, silu_fast(fmaf(ai, w1b, b1b)), accB);
        }
    }
    if (ja < F1) aggh[(size_t)n * F1 + ja] = accA;
    if (jb < F1) aggh[(size_t)n * F1 + jb] = accB;
}
#define HP_NODES 20
#define HP_KT 25
__global__ __launch_bounds__(256) void k_h2_pool3(
    const float* __restrict__ aggh, const float* __restrict__ W2, const float* __restrict__ b2,
    const int* __restrict__ batch, int N, double* __restrict__ pooled) {
    __shared__ float smem[HP_KT * F2 + HP_NODES * (F1 + 1)];
    float* sW = smem;
    float* sA = smem + HP_KT * F2;
    float* sOut = smem;
    __shared__ int sbatch[HP_NODES];
    int tid = threadIdx.x;
    int base = blockIdx.x * HP_NODES;
    for (int idx = tid; idx < HP_NODES * (F1 / 4); idx += 256) {
        int i = idx / (F1 / 4), q = idx % (F1 / 4);
        int n = base + i;
        float4 v = make_float4(0.f, 0.f, 0.f, 0.f);
        if (n < N) v = *(const float4*)(aggh + (size_t)n * F1 + q * 4);
        float* dp = &sA[i * (F1 + 1) + q * 4];
        dp[0] = v.x; dp[1] = v.y; dp[2] = v.z; dp[3] = v.w;
    }
    if (tid < HP_NODES) {
        int n = base + tid;
        sbatch[tid] = (n < N) ? batch[n] : -1;
    }
    const int fgrp = tid % 50;
    const int ngrp = tid / 50;
    const int m0 = fgrp * 4;
    const int i0 = ngrp * 4;
    const bool act = (tid < 250);
    float acc[4][4];
    #pragma unroll
    for (int i = 0; i < 4; ++i)
        #pragma unroll
        for (int j = 0; j < 4; ++j) acc[i][j] = 0.0f;
    for (int kt = 0; kt < F1; kt += HP_KT) {
        __syncthreads();
        for (int idx = tid; idx < (HP_KT * F2) / 4; idx += 256)
            ((float4*)sW)[idx] = ((const float4*)(W2 + (size_t)kt * F2))[idx];
        __syncthreads();
        if (act) {
            #pragma unroll
            for (int kk = 0; kk < HP_KT; ++kk) {
                float4 w = *(const float4*)&sW[kk * F2 + m0];
                int k = kt + kk;
                float a0 = sA[(i0 + 0) * (F1 + 1) + k];
                float a1 = sA[(i0 + 1) * (F1 + 1) + k];
                float a2 = sA[(i0 + 2) * (F1 + 1) + k];
                float a3 = sA[(i0 + 3) * (F1 + 1) + k];
                acc[0][0] = fmaf(a0, w.x, acc[0][0]); acc[0][1] = fmaf(a0, w.y, acc[0][1]);
                acc[0][2] = fmaf(a0, w.z, acc[0][2]); acc[0][3] = fmaf(a0, w.w, acc[0][3]);
                acc[1][0] = fmaf(a1, w.x, acc[1][0]); acc[1][1] = fmaf(a1, w.y, acc[1][1]);
                acc[1][2] = fmaf(a1, w.z, acc[1][2]); acc[1][3] = fmaf(a1, w.w, acc[1][3]);
                acc[2][0] = fmaf(a2, w.x, acc[2][0]); acc[2][1] = fmaf(a2, w.y, acc[2][1]);
                acc[2][2] = fmaf(a2, w.z, acc[2][2]); acc[2][3] = fmaf(a2, w.w, acc[2][3]);
                acc[3][0] = fmaf(a3, w.x, acc[3][0]); acc[3][1] = fmaf(a3, w.y, acc[3][1]);
                acc[3][2] = fmaf(a3, w.z, acc[3][2]); acc[3][3] = fmaf(a3, w.w, acc[3][3]);
            }
        }
    }
    __syncthreads();
    if (act) {
        float4 bb = *(const float4*)(b2 + m0);
        #pragma unroll
        for (int i = 0; i < 4; ++i) {
            float4 r;
            r.x = siluf(acc[i][0] + bb.x);
            r.y = siluf(acc[i][1] + bb.y);
            r.z = siluf(acc[i][2] + bb.z);
            r.w = siluf(acc[i][3] + bb.w);
            *(float4*)&sOut[(i0 + i) * F2 + m0] = r;
        }
    }
    __syncthreads();
    if (tid < F2) {
        double pl = 0.0;
        int gcur = -1;
        for (int i = 0; i < HP_NODES; ++i) {
            int n = base + i;
            if (n >= N) break;
            int g = sbatch[i];
            if (g != gcur) {
                if (gcur >= 0) atomicAdd(&pooled[(size_t)gcur * F2 + tid], pl);
                pl = 0.0;
                gcur = g;
            }
            pl += (double)sOut[i * F2 + tid];
        }
        if (gcur >= 0) atomicAdd(&pooled[(size_t)gcur * F2 + tid], pl);
    }
}

// Head MLP: one block per graph, double precision.
__global__ __launch_bounds__(256) void k_head(
    const double* __restrict__ pooled, const int* __restrict__ counts,
    const float* __restrict__ Wl1, const float* __restrict__ bl1,
    const float* __restrict__ Wl2, const float* __restrict__ bl2,
    float* __restrict__ out) {
    int g = blockIdx.x;
    int tid = threadIdx.x;
    __shared__ double sp[F2];
    __shared__ double red[256];
    double icnt = 1.0 / (double)max(counts[g], 1);
    for (int m = tid; m < F2; m += 256) sp[m] = pooled[(size_t)g * F2 + m] * icnt;
    __syncthreads();
    double part = 0.0;
    if (tid < 100) {
        double acc = (double)bl1[tid];
        #pragma unroll 4
        for (int m = 0; m < F2; ++m) acc += sp[m] * (double)Wl1[m * 100 + tid];
        double t1 = acc / (1.0 + exp(-acc));
        part = t1 * (double)Wl2[tid];
    }
    red[tid] = part;
    __syncthreads();
    for (int s = 128; s > 0; s >>= 1) {
        if (tid < s) red[tid] += red[tid + s];
        __syncthreads();
    }
    if (tid == 0) out[g] = (float)(red[0] + (double)bl2[0]);
}

extern "C" void kernel_launch(void* const* d_in, const int* in_sizes, int n_in,
                              void* d_out, int out_size, void* d_ws, size_t ws_size,
                              hipStream_t stream)
{
    const float* x   = (const float*)d_in[0];
    const int*   src = (const int*)d_in[1];
    const int*   dst = (const int*)d_in[2];
    const int*   batch = (const int*)d_in[3];
    const float* W1  = (const float*)d_in[4];
    const float* b1  = (const float*)d_in[5];
    const float* W2  = (const float*)d_in[6];
    const float* b2  = (const float*)d_in[7];
    const float* Wl1 = (const float*)d_in[8];
    const float* bl1 = (const float*)d_in[9];
    const float* Wl2 = (const float*)d_in[10];
    const float* bl2 = (const float*)d_in[11];
    int N = in_sizes[0];
    int E = in_sizes[1];
    int G = out_size;
    float* out = (float*)d_out;

    char* ws = (char*)d_ws;
    size_t o = 0;
    auto alloc = [&](size_t bytes) -> void* {
        o = (o + 255) & ~(size_t)255;
        void* p = ws + o;
        o += bytes;
        return p;
    };
    int nscan = (N + SCHUNK - 1) / SCHUNK;
    int nbk = (N + BW - 1) / BW;
    int*    deg    = (int*)alloc((size_t)N * 4);
    int*    cursor = (int*)alloc((size_t)N * 4);
    int*    off    = (int*)alloc((size_t)(N + 1) * 4);
    int*    nbr    = (int*)alloc((size_t)E * 4);
    float*  dinv   = (float*)alloc((size_t)N * 4);
    float*  aggx   = (float*)alloc((size_t)N * 4);   // fallback only
    float*  yv     = (float*)alloc((size_t)N * 4);   // y = x*dinv (bucket path)
    float*  aggh   = (float*)alloc((size_t)N * F1 * 4);  // fallback only
    double* pooled = (double*)alloc((size_t)G * F2 * 8);
    int*    counts = (int*)alloc((size_t)G * 4);
    int*    starts = (int*)alloc((size_t)(G + 1) * 4);
    int*    partials = (int*)alloc((size_t)nscan * 4);
    int*    bcnt   = (int*)alloc((size_t)nbk * 4);
    int*    bbase  = (int*)alloc((size_t)(nbk + 1) * 4);
    int*    bcur   = (int*)alloc((size_t)nbk * 4);
    float2* aggxd  = (float2*)alloc((size_t)N * 8);
    float*  Dmat   = (float*)alloc((size_t)KM * F2 * 4);
    double* clbuf  = (double*)alloc((size_t)KM * F1 * 8);
    float*  scal   = (float*)alloc(2 * 4);
    unsigned* amaxb = (unsigned*)alloc(4);
    int*    gbar   = (int*)alloc(8 * 4);
    // gated large buffer: bucketed edge pairs (last)
    o = (o + 255) & ~(size_t)255;
    unsigned long long* pairs = (unsigned long long*)(ws + o);
    bool use_bucket = ((o + (size_t)E * 8) <= ws_size) && (nbk <= 512);

    int tE = (E + 255) / 256;
    int tN = (N + 255) / 256;

    if (use_bucket) {
        k_prep<<<PREP_BLOCKS, 256, 0, stream>>>(batch, N, G, nbk, starts, counts, pooled, bcnt, amaxb, gbar);
        k_bucket_build<<<GB_BLOCKS, 512, 0, stream>>>(
            src, dst, x, N, E, nbk, bcnt, bbase, bcur, pairs,
            dinv, yv, off, nbr, aggxd, amaxb, gbar);
        k_fit_coef<<<F1, 64, 0, stream>>>(W1, b1, amaxb, clbuf, scal);
        k_fit_fold<<<(KM * F2 + 255) / 256, 256, 0, stream>>>(clbuf, W2, Dmat);
        k_h2_pool7<<<(N + P7_NODES - 1) / P7_NODES, 256, 0, stream>>>(
            off, nbr, aggxd, scal, Dmat, b2, batch, N, pooled);
    } else {
        k_prep<<<PREP_BLOCKS, 256, 0, stream>>>(batch, N, G, nbk, starts, counts, pooled, bcnt, amaxb, gbar);
        hipMemsetAsync(deg, 0, (size_t)N * 4, stream);
        hipMemsetAsync(cursor, 0, (size_t)N * 4, stream);
        k_count_deg<<<tE, 256, 0, stream>>>(dst, E, deg);
        k_dinv_self<<<tN, 256, 0, stream>>>(deg, x, N, dinv, aggx);
        k_scan_partial<<<nscan, 256, 0, stream>>>(deg, N, partials);
        k_scan_blocks<<<1, 1024, 0, stream>>>(partials, nscan);
        k_scan_final<<<nscan, 256, 0, stream>>>(deg, N, partials, off);
        k_fill_agg<<<tE, 256, 0, stream>>>(src, dst, E, off, cursor, nbr, x, dinv, aggx);
        k_aggh<<<(N + 3) / 4, 256, 0, stream>>>(off, nbr, aggx, dinv, W1, b1, N, aggh);
        k_h2_pool3<<<(N + HP_NODES - 1) / HP_NODES, 256, 0, stream>>>(aggh, W2, b2, batch, N, pooled);
    }
    k_head<<<G, 256, 0, stream>>>(pooled, counts, Wl1, bl1, Wl2, bl2, out);
}

// Round 22
// 139.399 us; speedup vs baseline: 1.3715x; 1.3715x over previous
//
#include <hip/hip_runtime.h>
#include <math.h>

#define F1 100
#define F2 200
#define KM 12          // Chebyshev moments (rho~17 => trunc far below fp32 roundoff)
#define BW_LOG 9
#define BW 512

__device__ __forceinline__ float siluf(float v) {
    return v / (1.0f + expf(-v));   // precise
}
__device__ __forceinline__ float silu_fast(float v) {
    return __fdividef(v, 1.0f + __expf(-v));
}

// Fused prologue: batch bounds (block 0) + zero pooled (all blocks) + zero bcnt/amax (block 1).
#define PREP_BLOCKS 16
__global__ __launch_bounds__(256) void k_prep(
    const int* __restrict__ batch, int N, int G, int nbk,
    int* __restrict__ starts, int* __restrict__ counts,
    double* __restrict__ pooled, int* __restrict__ bcnt, unsigned* __restrict__ amax) {
    int t = threadIdx.x;
    int b = blockIdx.x;
    for (int idx = b * 256 + t; idx < G * F2; idx += PREP_BLOCKS * 256)
        pooled[idx] = 0.0;
    if (b == 1) {
        for (int i = t; i < nbk; i += 256) bcnt[i] = 0;
        if (t == 0) *amax = 0u;
    }
    if (b == 0) {
        if (t <= G) {
            int lo = 0, hi = N;
            while (lo < hi) {
                int mid = (lo + hi) >> 1;
                if (batch[mid] < t) lo = mid + 1; else hi = mid;
            }
            starts[t] = lo;
        }
        __syncthreads();
        if (t < G) counts[t] = starts[t + 1] - starts[t];
    }
}

// ---- bucketed CSR build ----
__global__ __launch_bounds__(256) void k_bucket_count(const int* __restrict__ dst, int E,
                                                      int nbk, int* __restrict__ gcnt) {
    extern __shared__ int cnt[];
    for (int i = threadIdx.x; i < nbk; i += 256) cnt[i] = 0;
    __syncthreads();
    for (int e = blockIdx.x * 256 + threadIdx.x; e < E; e += gridDim.x * 256)
        atomicAdd(&cnt[dst[e] >> BW_LOG], 1);
    __syncthreads();
    for (int i = threadIdx.x; i < nbk; i += 256)
        if (cnt[i]) atomicAdd(&gcnt[i], cnt[i]);
}

__global__ __launch_bounds__(256) void k_bucket_scan(const int* __restrict__ gcnt, int nbk, int E,
                                                     int* __restrict__ base, int* __restrict__ cursor) {
    __shared__ int sh[256];
    int t = threadIdx.x;
    int v = (t < nbk) ? gcnt[t] : 0;
    sh[t] = v;
    __syncthreads();
    for (int ofs = 1; ofs < 256; ofs <<= 1) {
        int u = (t >= ofs) ? sh[t - ofs] : 0;
        __syncthreads();
        sh[t] += u;
        __syncthreads();
    }
    if (t < nbk) { int ex = sh[t] - v; base[t] = ex; cursor[t] = ex; }
    if (t == 0) base[nbk] = E;
}

#define CROUND 4096
#define CEPT 16
__global__ __launch_bounds__(256) void k_bucket_scatter(
    const int* __restrict__ src, const int* __restrict__ dst, int E, int nbk,
    int* __restrict__ gcursor, unsigned long long* __restrict__ pairs) {
    __shared__ int cnt[256];
    __shared__ int scanb[256];
    __shared__ int startx[256];
    __shared__ int cur[256];
    __shared__ int gbase[256];
    __shared__ unsigned long long stage[CROUND];
    int tid = threadIdx.x;
    for (long long r0 = (long long)blockIdx.x * CROUND; r0 < E; r0 += (long long)gridDim.x * CROUND) {
        cnt[tid] = 0;
        __syncthreads();
        int ss[CEPT], dd[CEPT], bb[CEPT];
        bool va[CEPT];
        #pragma unroll
        for (int j = 0; j < CEPT; ++j) {
            long long e = r0 + j * 256 + tid;
            va[j] = (e < E);
            if (va[j]) {
                ss[j] = src[e]; dd[j] = dst[e]; bb[j] = dd[j] >> BW_LOG;
                atomicAdd(&cnt[bb[j]], 1);
            }
        }
        __syncthreads();
        scanb[tid] = cnt[tid];
        __syncthreads();
        for (int ofs = 1; ofs < 256; ofs <<= 1) {
            int u = (tid >= ofs) ? scanb[tid - ofs] : 0;
            __syncthreads();
            scanb[tid] += u;
            __syncthreads();
        }
        int ex = scanb[tid] - cnt[tid];
        startx[tid] = ex;
        cur[tid] = ex;
        if (tid < nbk && cnt[tid] > 0) gbase[tid] = atomicAdd(&gcursor[tid], cnt[tid]);
        __syncthreads();
        int total = scanb[255];
        #pragma unroll
        for (int j = 0; j < CEPT; ++j) {
            if (va[j]) {
                int slot = atomicAdd(&cur[bb[j]], 1);
                stage[slot] = ((unsigned long long)(unsigned)dd[j] << 32) | (unsigned)ss[j];
            }
        }
        __syncthreads();
        for (int i = tid; i < total; i += 256) {
            unsigned long long p = stage[i];
            int b = (int)(p >> 32) >> BW_LOG;
            pairs[gbase[b] + (i - startx[b])] = p;
        }
        __syncthreads();
    }
}

// deg histogram + dinv + y=x*dinv + intra-bucket scan -> global CSR off
__global__ __launch_bounds__(512) void k_bucket_degoff(
    const unsigned long long* __restrict__ pairs, const int* __restrict__ bbase,
    const float* __restrict__ x, int N,
    float* __restrict__ dinv, float* __restrict__ y, int* __restrict__ off) {
    __shared__ int dl[BW];
    __shared__ int sc[BW];
    int b = blockIdx.x;
    int t = threadIdx.x;
    dl[t] = 0;
    __syncthreads();
    int beg = bbase[b], end = bbase[b + 1];
    for (int i = beg + t; i < end; i += 512)
        atomicAdd(&dl[(int)(pairs[i] >> 32) & (BW - 1)], 1);
    __syncthreads();
    int node = (b << BW_LOG) + t;
    int dg = dl[t];
    if (node < N) {
        float d = 1.0f / sqrtf((float)dg + 1.0f);
        dinv[node] = d;
        y[node] = x[node] * d;
    }
    sc[t] = dg;
    __syncthreads();
    for (int ofs = 1; ofs < BW; ofs <<= 1) {
        int u = (t >= ofs) ? sc[t - ofs] : 0;
        __syncthreads();
        sc[t] += u;
        __syncthreads();
    }
    if (node < N) off[node] = beg + sc[t] - dg;
    if (node == N - 1) off[N] = beg + sc[t];
}

// CSR fill (LDS cursors) + layer-1 scalar agg (single random read y[s]) -> aggxd; block-max -> amax.
__global__ __launch_bounds__(512) void k_bucket_fill(
    const unsigned long long* __restrict__ pairs, const int* __restrict__ bbase,
    const int* __restrict__ off, const float* __restrict__ y, const float* __restrict__ dinv,
    int N, int* __restrict__ nbr, float2* __restrict__ aggxd, unsigned* __restrict__ amax) {
    __shared__ int offl[BW];
    __shared__ int cur[BW];
    __shared__ float agg[BW];
    int b = blockIdx.x;
    int t = threadIdx.x;
    int node0 = b << BW_LOG;
    int node = node0 + t;
    offl[t] = (node < N) ? off[node] : 0;
    cur[t] = 0;
    agg[t] = 0.0f;
    __syncthreads();
    int beg = bbase[b], end = bbase[b + 1];
    for (int i = beg + t; i < end; i += 512) {
        unsigned long long p = pairs[i];
        int s = (int)(p & 0xffffffffu);
        int d = (int)(p >> 32);
        int l = d & (BW - 1);
        int pos = atomicAdd(&cur[l], 1);
        nbr[offl[l] + pos] = s;
        atomicAdd(&agg[l], y[s]);
    }
    __syncthreads();
    float av = 0.0f;
    if (node < N) {
        float dn = dinv[node];
        float a = dn * (agg[t] + y[node]);
        aggxd[node] = make_float2(a, dn);
        av = fabsf(a);
    }
    __syncthreads();
    agg[t] = av;
    __syncthreads();
    for (int ofs = 256; ofs > 0; ofs >>= 1) {
        if (t < ofs) agg[t] = fmaxf(agg[t], agg[t + ofs]);
        __syncthreads();
    }
    if (t == 0) atomicMax(amax, __float_as_uint(agg[0]));
}

// Fit stage 1: Chebyshev coefficients cl[k][j] of g(a,j)=silu(a*W1[j]+b1[j]) on [-A,A].
__global__ __launch_bounds__(64) void k_fit_coef(
    const float* __restrict__ W1, const float* __restrict__ b1,
    const unsigned* __restrict__ amax_bits,
    double* __restrict__ cl /* [KM][F1] */, float* __restrict__ scal /* {A, invA} */) {
    int j = blockIdx.x;
    int i = threadIdx.x;
    float A = __uint_as_float(*amax_bits);
    if (!(A > 0.0f)) A = 1.0f;
    A *= 1.000001f;
    if (j == 0 && i == 0) { scal[0] = A; scal[1] = 1.0f / A; }
    const double PI = 3.14159265358979323846;
    double th = (i + 0.5) * (PI / 64.0);
    double xx = cos(th);
    double w = (double)W1[j] * (double)A;
    double u = w * xx + (double)b1[j];
    double f = u / (1.0 + exp(-u));
    double acc[KM];
    {
        double c0 = 1.0, c1 = xx;
        acc[0] = f;
        acc[1] = f * xx;
        #pragma unroll
        for (int k = 2; k < KM; ++k) {
            double c2 = 2.0 * xx * c1 - c0;
            acc[k] = f * c2;
            c0 = c1; c1 = c2;
        }
    }
    #pragma unroll
    for (int k = 0; k < KM; ++k) {
        double v = acc[k];
        for (int ofs = 32; ofs > 0; ofs >>= 1)
            v += __shfl_down(v, ofs);
        if (i == 0) cl[k * F1 + j] = v * ((k == 0 ? 1.0 : 2.0) / 64.0);
    }
}

// Fit stage 2: fold through W2: D[k][m] = sum_j cl[k][j] * W2[j][m].
__global__ __launch_bounds__(256) void k_fit_fold(
    const double* __restrict__ cl, const float* __restrict__ W2,
    float* __restrict__ Dmat /* [KM][F2] */) {
    __shared__ double scl[KM * F1];
    int tid = threadIdx.x;
    for (int idx = tid; idx < KM * F1; idx += 256) scl[idx] = cl[idx];
    __syncthreads();
    int idx = blockIdx.x * 256 + tid;
    if (idx >= KM * F2) return;
    int k = idx / F2, m = idx % F2;
    double s = 0.0;
    #pragma unroll 4
    for (int j = 0; j < F1; ++j)
        s += scl[k * F1 + j] * (double)W2[j * F2 + m];
    Dmat[idx] = (float)s;
}

// Fused moments + h2 + graph mean-pool: one block per 32 nodes.
#define P7_NODES 32
__global__ __launch_bounds__(256) void k_h2_pool7(
    const int* __restrict__ off, const int* __restrict__ nbr,
    const float2* __restrict__ aggxd, const float* __restrict__ scal,
    const float* __restrict__ Dmat, const float* __restrict__ b2,
    const int* __restrict__ batch, int N, double* __restrict__ pooled) {
    __shared__ float sM[P7_NODES][KM];   // 1.5 KB
    __shared__ int sbatch[P7_NODES];
    int tid = threadIdx.x;
    int base = blockIdx.x * P7_NODES;
    if (tid < P7_NODES) {
        int n = base + tid;
        sbatch[tid] = (n < N) ? batch[n] : -1;
    }
    int m = tid;
    bool act = (m < F2);
    float4 d4[KM / 4];
    float bb = 0.0f;
    if (act) {
        #pragma unroll
        for (int k = 0; k < KM / 4; ++k) {
            d4[k].x = Dmat[(4 * k + 0) * F2 + m];
            d4[k].y = Dmat[(4 * k + 1) * F2 + m];
            d4[k].z = Dmat[(4 * k + 2) * F2 + m];
            d4[k].w = Dmat[(4 * k + 3) * F2 + m];
        }
        bb = b2[m];
    }
    // ---- phase 1: moments for this block's 32 nodes (8 threads/node) ----
    {
        int g = tid >> 3;
        int l = tid & 7;
        int node = base + g;
        float invA = scal[1];
        float u[KM];
        #pragma unroll
        for (int k = 0; k < KM; ++k) u[k] = 0.0f;
        if (node < N) {
            int beg = off[node], end = off[node + 1];
            for (int e = beg + l; e < end; e += 8) {
                int s = nbr[e];
                float2 q = aggxd[s];
                float w = q.y;
                float xa = q.x * invA;
                float tx = xa + xa;
                float c0 = 1.0f, c1 = xa;
                u[0] += w;
                u[1] = fmaf(w, c1, u[1]);
                #pragma unroll
                for (int k = 2; k < KM; ++k) {
                    float c2 = fmaf(tx, c1, -c0);
                    u[k] = fmaf(w, c2, u[k]);
                    c0 = c1; c1 = c2;
                }
            }
        }
        #pragma unroll
        for (int k = 0; k < KM; ++k) {
            u[k] += __shfl_down(u[k], 4, 8);
            u[k] += __shfl_down(u[k], 2, 8);
            u[k] += __shfl_down(u[k], 1, 8);
        }
        if (l == 0 && node < N) {
            float2 sd = aggxd[node];
            float d0 = sd.y;
            float d00 = d0 * d0;
            float xa = sd.x * invA;
            float tx = xa + xa;
            float c0 = 1.0f, c1 = xa;
            sM[g][0] = fmaf(d0, u[0], d00);
            sM[g][1] = fmaf(d0, u[1], d00 * xa);
            #pragma unroll
            for (int k = 2; k < KM; ++k) {
                float c2 = fmaf(tx, c1, -c0);
                sM[g][k] = fmaf(d0, u[k], d00 * c2);
                c0 = c1; c1 = c2;
            }
        }
    }
    __syncthreads();
    // ---- phase 2: h2 + pooling (2-node ILP unroll) ----
    double pl = 0.0;
    int gcur = -1;
    int nlim = min(P7_NODES, N - base);
    int i = 0;
    for (; i + 1 < nlim; i += 2) {
        float p0 = bb, p1 = 0.f, p2 = 0.f, p3 = 0.f;
        float q0 = bb, q1 = 0.f, q2 = 0.f, q3 = 0.f;
        const float4* mA = (const float4*)&sM[i][0];
        const float4* mB = (const float4*)&sM[i + 1][0];
        #pragma unroll
        for (int k = 0; k < KM / 4; ++k) {
            float4 a = mA[k];
            float4 c = mB[k];
            p0 = fmaf(a.x, d4[k].x, p0); q0 = fmaf(c.x, d4[k].x, q0);
            p1 = fmaf(a.y, d4[k].y, p1); q1 = fmaf(c.y, d4[k].y, q1);
            p2 = fmaf(a.z, d4[k].z, p2); q2 = fmaf(c.z, d4[k].z, q2);
            p3 = fmaf(a.w, d4[k].w, p3); q3 = fmaf(c.w, d4[k].w, q3);
        }
        float preA = (p0 + p1) + (p2 + p3);
        float preB = (q0 + q1) + (q2 + q3);
        float hA = silu_fast(preA);
        float hB = silu_fast(preB);
        int g = sbatch[i];
        if (g != gcur) {
            if (gcur >= 0 && act) atomicAdd(&pooled[(size_t)gcur * F2 + m], pl);
            pl = 0.0;
            gcur = g;
        }
        if (act) pl += (double)hA;
        g = sbatch[i + 1];
        if (g != gcur) {
            if (gcur >= 0 && act) atomicAdd(&pooled[(size_t)gcur * F2 + m], pl);
            pl = 0.0;
            gcur = g;
        }
        if (act) pl += (double)hB;
    }
    if (i < nlim) {
        float p0 = bb, p1 = 0.f, p2 = 0.f, p3 = 0.f;
        const float4* mA = (const float4*)&sM[i][0];
        #pragma unroll
        for (int k = 0; k < KM / 4; ++k) {
            float4 a = mA[k];
            p0 = fmaf(a.x, d4[k].x, p0);
            p1 = fmaf(a.y, d4[k].y, p1);
            p2 = fmaf(a.z, d4[k].z, p2);
            p3 = fmaf(a.w, d4[k].w, p3);
        }
        float pre = (p0 + p1) + (p2 + p3);
        int g = sbatch[i];
        if (g != gcur) {
            if (gcur >= 0 && act) atomicAdd(&pooled[(size_t)gcur * F2 + m], pl);
            pl = 0.0;
            gcur = g;
        }
        if (act) pl += (double)silu_fast(pre);
    }
    if (gcur >= 0 && act) atomicAdd(&pooled[(size_t)gcur * F2 + m], pl);
}

// ---- fallback path kernels (ws too small for pairs) ----
#define SCHUNK 2048
__global__ __launch_bounds__(256) void k_scan_partial(const int* __restrict__ deg, int N,
                                                      int* __restrict__ partials) {
    __shared__ int red[256];
    int base = blockIdx.x * SCHUNK;
    int s = 0;
    for (int i = threadIdx.x; i < SCHUNK; i += 256) {
        int idx = base + i;
        if (idx < N) s += deg[idx];
    }
    red[threadIdx.x] = s;
    __syncthreads();
    for (int ofs = 128; ofs > 0; ofs >>= 1) {
        if (threadIdx.x < ofs) red[threadIdx.x] += red[threadIdx.x + ofs];
        __syncthreads();
    }
    if (threadIdx.x == 0) partials[blockIdx.x] = red[0];
}
__global__ __launch_bounds__(1024) void k_scan_blocks(int* __restrict__ partials, int nb) {
    __shared__ int sh[1024];
    int t = threadIdx.x;
    int v = (t < nb) ? partials[t] : 0;
    sh[t] = v;
    __syncthreads();
    for (int ofs = 1; ofs < 1024; ofs <<= 1) {
        int u = (t >= ofs) ? sh[t - ofs] : 0;
        __syncthreads();
        sh[t] += u;
        __syncthreads();
    }
    if (t < nb) partials[t] = sh[t] - v;
}
__global__ __launch_bounds__(256) void k_scan_final(const int* __restrict__ deg, int N,
                                                    const int* __restrict__ partials,
                                                    int* __restrict__ off) {
    __shared__ int sh[256];
    int base = blockIdx.x * SCHUNK;
    int i0 = base + threadIdx.x * 8;
    int v[8];
    int s = 0;
    #pragma unroll
    for (int j = 0; j < 8; ++j) {
        int idx = i0 + j;
        v[j] = (idx < N) ? deg[idx] : 0;
        s += v[j];
    }
    int mine = s;
    sh[threadIdx.x] = s;
    __syncthreads();
    for (int ofs = 1; ofs < 256; ofs <<= 1) {
        int u = (threadIdx.x >= ofs) ? sh[threadIdx.x - ofs] : 0;
        __syncthreads();
        sh[threadIdx.x] += u;
        __syncthreads();
    }
    int run = partials[blockIdx.x] + sh[threadIdx.x] - mine;
    #pragma unroll
    for (int j = 0; j < 8; ++j) {
        int idx = i0 + j;
        if (idx < N) { off[idx] = run; run += v[j]; }
    }
    if (N >= i0 && N <= i0 + 8) off[N] = run;
}
__global__ void k_count_deg(const int* __restrict__ dst, int E, int* __restrict__ deg) {
    int i = blockIdx.x * blockDim.x + threadIdx.x;
    if (i < E) atomicAdd(&deg[dst[i]], 1);
}
__global__ void k_dinv_self(const int* __restrict__ deg, const float* __restrict__ x, int N,
                            float* __restrict__ dinv, float* __restrict__ aggx) {
    int i = blockIdx.x * blockDim.x + threadIdx.x;
    if (i < N) {
        float d = 1.0f / sqrtf((float)deg[i] + 1.0f);
        dinv[i] = d;
        aggx[i] = x[i] * d * d;
    }
}
__global__ void k_fill_agg(const int* __restrict__ src, const int* __restrict__ dst, int E,
                           const int* __restrict__ off, int* __restrict__ cursor,
                           int* __restrict__ nbr,
                           const float* __restrict__ x, const float* __restrict__ dinv,
                           float* __restrict__ aggx) {
    int e = blockIdx.x * blockDim.x + threadIdx.x;
    if (e < E) {
        int s = src[e], d = dst[e];
        int p = atomicAdd(&cursor[d], 1);
        nbr[off[d] + p] = s;
        atomicAdd(&aggx[d], x[s] * dinv[s] * dinv[d]);
    }
}
__global__ __launch_bounds__(256) void k_aggh(
    const int* __restrict__ off, const int* __restrict__ nbr,
    const float* __restrict__ aggx, const float* __restrict__ dinv,
    const float* __restrict__ W1, const float* __restrict__ b1,
    int N, float* __restrict__ aggh) {
    int wave = threadIdx.x >> 6;
    int lane = threadIdx.x & 63;
    int n = blockIdx.x * 4 + wave;
    if (n >= N) return;
    int ja = lane, jb = lane + 64;
    float w1a = (ja < F1) ? W1[ja] : 0.0f;
    float b1a = (ja < F1) ? b1[ja] : 0.0f;
    float w1b = (jb < F1) ? W1[jb] : 0.0f;
    float b1b = (jb < F1) ? b1[jb] : 0.0f;
    float d0 = dinv[n];
    float a0 = aggx[n];
    float accA = silu_fast(fmaf(a0, w1a, b1a)) * (d0 * d0);
    float accB = silu_fast(fmaf(a0, w1b, b1b)) * (d0 * d0);
    int beg = off[n], end = off[n + 1];
    for (int t = beg; t < end; t += 64) {
        int cnt = min(64, end - t);
        float sa = 0.0f, sw = 0.0f;
        if (lane < cnt) {
            int s = nbr[t + lane];
            sa = aggx[s];
            sw = dinv[s] * d0;
        }
        for (int i = 0; i < cnt; ++i) {
            float ai = __shfl(sa, i);
            float wi = __shfl(sw, i);
            accA = fmaf(wi, silu_fast(fmaf(ai, w1a, b1a)), accA);
            accB = fmaf(wi, silu_fast(fmaf(ai, w1b, b1b)), accB);
        }
    }
    if (ja < F1) aggh[(size_t)n * F1 + ja] = accA;
    if (jb < F1) aggh[(size_t)n * F1 + jb] = accB;
}
#define HP_NODES 20
#define HP_KT 25
__global__ __launch_bounds__(256) void k_h2_pool3(
    const float* __restrict__ aggh, const float* __restrict__ W2, const float* __restrict__ b2,
    const int* __restrict__ batch, int N, double* __restrict__ pooled) {
    __shared__ float smem[HP_KT * F2 + HP_NODES * (F1 + 1)];
    float* sW = smem;
    float* sA = smem + HP_KT * F2;
    float* sOut = smem;
    __shared__ int sbatch[HP_NODES];
    int tid = threadIdx.x;
    int base = blockIdx.x * HP_NODES;
    for (int idx = tid; idx < HP_NODES * (F1 / 4); idx += 256) {
        int i = idx / (F1 / 4), q = idx % (F1 / 4);
        int n = base + i;
        float4 v = make_float4(0.f, 0.f, 0.f, 0.f);
        if (n < N) v = *(const float4*)(aggh + (size_t)n * F1 + q * 4);
        float* dp = &sA[i * (F1 + 1) + q * 4];
        dp[0] = v.x; dp[1] = v.y; dp[2] = v.z; dp[3] = v.w;
    }
    if (tid < HP_NODES) {
        int n = base + tid;
        sbatch[tid] = (n < N) ? batch[n] : -1;
    }
    const int fgrp = tid % 50;
    const int ngrp = tid / 50;
    const int m0 = fgrp * 4;
    const int i0 = ngrp * 4;
    const bool act = (tid < 250);
    float acc[4][4];
    #pragma unroll
    for (int i = 0; i < 4; ++i)
        #pragma unroll
        for (int j = 0; j < 4; ++j) acc[i][j] = 0.0f;
    for (int kt = 0; kt < F1; kt += HP_KT) {
        __syncthreads();
        for (int idx = tid; idx < (HP_KT * F2) / 4; idx += 256)
            ((float4*)sW)[idx] = ((const float4*)(W2 + (size_t)kt * F2))[idx];
        __syncthreads();
        if (act) {
            #pragma unroll
            for (int kk = 0; kk < HP_KT; ++kk) {
                float4 w = *(const float4*)&sW[kk * F2 + m0];
                int k = kt + kk;
                float a0 = sA[(i0 + 0) * (F1 + 1) + k];
                float a1 = sA[(i0 + 1) * (F1 + 1) + k];
                float a2 = sA[(i0 + 2) * (F1 + 1) + k];
                float a3 = sA[(i0 + 3) * (F1 + 1) + k];
                acc[0][0] = fmaf(a0, w.x, acc[0][0]); acc[0][1] = fmaf(a0, w.y, acc[0][1]);
                acc[0][2] = fmaf(a0, w.z, acc[0][2]); acc[0][3] = fmaf(a0, w.w, acc[0][3]);
                acc[1][0] = fmaf(a1, w.x, acc[1][0]); acc[1][1] = fmaf(a1, w.y, acc[1][1]);
                acc[1][2] = fmaf(a1, w.z, acc[1][2]); acc[1][3] = fmaf(a1, w.w, acc[1][3]);
                acc[2][0] = fmaf(a2, w.x, acc[2][0]); acc[2][1] = fmaf(a2, w.y, acc[2][1]);
                acc[2][2] = fmaf(a2, w.z, acc[2][2]); acc[2][3] = fmaf(a2, w.w, acc[2][3]);
                acc[3][0] = fmaf(a3, w.x, acc[3][0]); acc[3][1] = fmaf(a3, w.y, acc[3][1]);
                acc[3][2] = fmaf(a3, w.z, acc[3][2]); acc[3][3] = fmaf(a3, w.w, acc[3][3]);
            }
        }
    }
    __syncthreads();
    if (act) {
        float4 bb = *(const float4*)(b2 + m0);
        #pragma unroll
        for (int i = 0; i < 4; ++i) {
            float4 r;
            r.x = siluf(acc[i][0] + bb.x);
            r.y = siluf(acc[i][1] + bb.y);
            r.z = siluf(acc[i][2] + bb.z);
            r.w = siluf(acc[i][3] + bb.w);
            *(float4*)&sOut[(i0 + i) * F2 + m0] = r;
        }
    }
    __syncthreads();
    if (tid < F2) {
        double pl = 0.0;
        int gcur = -1;
        for (int i = 0; i < HP_NODES; ++i) {
            int n = base + i;
            if (n >= N) break;
            int g = sbatch[i];
            if (g != gcur) {
                if (gcur >= 0) atomicAdd(&pooled[(size_t)gcur * F2 + tid], pl);
                pl = 0.0;
                gcur = g;
            }
            pl += (double)sOut[i * F2 + tid];
        }
        if (gcur >= 0) atomicAdd(&pooled[(size_t)gcur * F2 + tid], pl);
    }
}

// Head MLP: one block per graph, double precision.
__global__ __launch_bounds__(256) void k_head(
    const double* __restrict__ pooled, const int* __restrict__ counts,
    const float* __restrict__ Wl1, const float* __restrict__ bl1,
    const float* __restrict__ Wl2, const float* __restrict__ bl2,
    float* __restrict__ out) {
    int g = blockIdx.x;
    int tid = threadIdx.x;
    __shared__ double sp[F2];
    __shared__ double red[256];
    double icnt = 1.0 / (double)max(counts[g], 1);
    for (int m = tid; m < F2; m += 256) sp[m] = pooled[(size_t)g * F2 + m] * icnt;
    __syncthreads();
    double part = 0.0;
    if (tid < 100) {
        double acc = (double)bl1[tid];
        #pragma unroll 4
        for (int m = 0; m < F2; ++m) acc += sp[m] * (double)Wl1[m * 100 + tid];
        double t1 = acc / (1.0 + exp(-acc));
        part = t1 * (double)Wl2[tid];
    }
    red[tid] = part;
    __syncthreads();
    for (int s = 128; s > 0; s >>= 1) {
        if (tid < s) red[tid] += red[tid + s];
        __syncthreads();
    }
    if (tid == 0) out[g] = (float)(red[0] + (double)bl2[0]);
}

extern "C" void kernel_launch(void* const* d_in, const int* in_sizes, int n_in,
                              void* d_out, int out_size, void* d_ws, size_t ws_size,
                              hipStream_t stream)
{
    const float* x   = (const float*)d_in[0];
    const int*   src = (const int*)d_in[1];
    const int*   dst = (const int*)d_in[2];
    const int*   batch = (const int*)d_in[3];
    const float* W1  = (const float*)d_in[4];
    const float* b1  = (const float*)d_in[5];
    const float* W2  = (const float*)d_in[6];
    const float* b2  = (const float*)d_in[7];
    const float* Wl1 = (const float*)d_in[8];
    const float* bl1 = (const float*)d_in[9];
    const float* Wl2 = (const float*)d_in[10];
    const float* bl2 = (const float*)d_in[11];
    int N = in_sizes[0];
    int E = in_sizes[1];
    int G = out_size;
    float* out = (float*)d_out;

    char* ws = (char*)d_ws;
    size_t o = 0;
    auto alloc = [&](size_t bytes) -> void* {
        o = (o + 255) & ~(size_t)255;
        void* p = ws + o;
        o += bytes;
        return p;
    };
    int nscan = (N + SCHUNK - 1) / SCHUNK;
    int nbk = (N + BW - 1) / BW;
    int*    deg    = (int*)alloc((size_t)N * 4);
    int*    cursor = (int*)alloc((size_t)N * 4);
    int*    off    = (int*)alloc((size_t)(N + 1) * 4);
    int*    nbr    = (int*)alloc((size_t)E * 4);
    float*  dinv   = (float*)alloc((size_t)N * 4);
    float*  aggx   = (float*)alloc((size_t)N * 4);   // fallback only
    float*  yv     = (float*)alloc((size_t)N * 4);   // y = x*dinv (bucket path)
    float*  aggh   = (float*)alloc((size_t)N * F1 * 4);  // fallback only
    double* pooled = (double*)alloc((size_t)G * F2 * 8);
    int*    counts = (int*)alloc((size_t)G * 4);
    int*    starts = (int*)alloc((size_t)(G + 1) * 4);
    int*    partials = (int*)alloc((size_t)nscan * 4);
    int*    bcnt   = (int*)alloc((size_t)nbk * 4);
    int*    bbase  = (int*)alloc((size_t)(nbk + 1) * 4);
    int*    bcur   = (int*)alloc((size_t)nbk * 4);
    float2* aggxd  = (float2*)alloc((size_t)N * 8);
    float*  Dmat   = (float*)alloc((size_t)KM * F2 * 4);
    double* clbuf  = (double*)alloc((size_t)KM * F1 * 8);
    float*  scal   = (float*)alloc(2 * 4);
    unsigned* amaxb = (unsigned*)alloc(4);
    // gated large buffer: bucketed edge pairs (last)
    o = (o + 255) & ~(size_t)255;
    unsigned long long* pairs = (unsigned long long*)(ws + o);
    bool use_bucket = (o + (size_t)E * 8) <= ws_size;

    int tE = (E + 255) / 256;
    int tN = (N + 255) / 256;

    if (use_bucket) {
        k_prep<<<PREP_BLOCKS, 256, 0, stream>>>(batch, N, G, nbk, starts, counts, pooled, bcnt, amaxb);
        k_bucket_count<<<240, 256, nbk * 4, stream>>>(dst, E, nbk, bcnt);
        k_bucket_scan<<<1, 256, 0, stream>>>(bcnt, nbk, E, bbase, bcur);
        k_bucket_scatter<<<240, 256, 0, stream>>>(src, dst, E, nbk, bcur, pairs);
        k_bucket_degoff<<<nbk, 512, 0, stream>>>(pairs, bbase, x, N, dinv, yv, off);
        k_bucket_fill<<<nbk, 512, 0, stream>>>(pairs, bbase, off, yv, dinv, N, nbr, aggxd, amaxb);
        k_fit_coef<<<F1, 64, 0, stream>>>(W1, b1, amaxb, clbuf, scal);
        k_fit_fold<<<(KM * F2 + 255) / 256, 256, 0, stream>>>(clbuf, W2, Dmat);
        k_h2_pool7<<<(N + P7_NODES - 1) / P7_NODES, 256, 0, stream>>>(
            off, nbr, aggxd, scal, Dmat, b2, batch, N, pooled);
    } else {
        k_prep<<<PREP_BLOCKS, 256, 0, stream>>>(batch, N, G, nbk, starts, counts, pooled, bcnt, amaxb);
        hipMemsetAsync(deg, 0, (size_t)N * 4, stream);
        hipMemsetAsync(cursor, 0, (size_t)N * 4, stream);
        k_count_deg<<<tE, 256, 0, stream>>>(dst, E, deg);
        k_dinv_self<<<tN, 256, 0, stream>>>(deg, x, N, dinv, aggx);
        k_scan_partial<<<nscan, 256, 0, stream>>>(deg, N, partials);
        k_scan_blocks<<<1, 1024, 0, stream>>>(partials, nscan);
        k_scan_final<<<nscan, 256, 0, stream>>>(deg, N, partials, off);
        k_fill_agg<<<tE, 256, 0, stream>>>(src, dst, E, off, cursor, nbr, x, dinv, aggx);
        k_aggh<<<(N + 3) / 4, 256, 0, stream>>>(off, nbr, aggx, dinv, W1, b1, N, aggh);
        k_h2_pool3<<<(N + HP_NODES - 1) / HP_NODES, 256, 0, stream>>>(aggh, W2, b2, batch, N, pooled);
    }
    k_head<<<G, 256, 0, stream>>>(pooled, counts, Wl1, bl1, Wl2, bl2, out);
}